// Round 6
// baseline (112.927 us; speedup 1.0000x reference)
//
#include <hip/hip_runtime.h>

// Chamfer distance, exact, spatially pruned (R5 bug fixed).
// R5 post-mortem: output was ~1.74x true value == "phase 2 never ran"
// signature. Root cause: W was sqrt(max of the |p|^2-SHIFTED mins
// u = -2p.q + |q|^2 = dist^2 - |p|^2, negative for nearly all points ->
// fmaxf(0, negatives) -> W ~ 0 -> phase-2 window clamped empty. Fix:
// W^2 = max_p (cm_p + u_p) (true dist^2), via shared atomicMax on
// float-as-int (valid: values clamped >= 0).
// Also: group-uniform compute skip so short ranges don't pay a full
// 2048-target padded chunk; dedicated pmin[] (no lds overlay);
// defined-behavior bucket_of (float clamp before int cast).

typedef float float2_t __attribute__((ext_vector_type(2)));
typedef float float4_t __attribute__((ext_vector_type(4)));

#define NB 1024
#define XLO_BND -4.5f
#define XSCALE (NB / 9.0f)

static __device__ __forceinline__ int bucket_of(float x) {
  float f = (x - XLO_BND) * XSCALE;
  f = fminf(fmaxf(f, 0.f), (float)(NB - 1));  // clamp BEFORE cast (fptosi UB)
  return (int)f;
}

// ---- packed fp32 FMA helpers (validated absmax 0.0 in R4) ----
// d = a * bcast_lo(b) + bcast_hi(b)   (b = {qz,qw}: d = a*qz + qw)
static __device__ __forceinline__ float2_t pk_fma_bl_bh(float2_t a, float2_t b) {
  float2_t d;
  asm("v_pk_fma_f32 %0, %1, %2, %2 op_sel:[0,0,1] op_sel_hi:[1,0,1]"
      : "=v"(d) : "v"(a), "v"(b));
  return d;
}
static __device__ __forceinline__ float2_t pk_fma_bh(float2_t a, float2_t b, float2_t c) {
  float2_t d;
  asm("v_pk_fma_f32 %0, %1, %2, %3 op_sel:[0,1,0] op_sel_hi:[1,1,1]"
      : "=v"(d) : "v"(a), "v"(b), "v"(c));
  return d;
}
static __device__ __forceinline__ float2_t pk_fma_bl(float2_t a, float2_t b, float2_t c) {
  float2_t d;
  asm("v_pk_fma_f32 %0, %1, %2, %3 op_sel:[0,0,0] op_sel_hi:[1,0,1]"
      : "=v"(d) : "v"(a), "v"(b), "v"(c));
  return d;
}

// ---- kernel A: per-cloud bucket sort by x (one block per cloud) ----
__global__ __launch_bounds__(1024) void bucket_sort_kernel(
    const float* __restrict__ pred, const float* __restrict__ target,
    float4_t* __restrict__ sorted, int* __restrict__ bstart, int M) {
  int c = blockIdx.x;  // cloud index: 2*b + (0=pred, 1=target)
  int b = c >> 1;
  const float* src = ((c & 1) ? target : pred) + (size_t)b * M * 3;
  __shared__ int hist[NB], sc[NB], cur[NB];
  int t = threadIdx.x;
  hist[t] = 0;
  __syncthreads();
  for (int i = t; i < M; i += 1024)
    atomicAdd(&hist[bucket_of(src[3 * i])], 1);
  __syncthreads();
  sc[t] = hist[t];
  __syncthreads();
  for (int off = 1; off < NB; off <<= 1) {  // Hillis-Steele inclusive scan
    int v = sc[t];
    if (t >= off) v += sc[t - off];
    __syncthreads();
    sc[t] = v;
    __syncthreads();
  }
  int excl = sc[t] - hist[t];
  bstart[c * (NB + 1) + t] = excl;
  if (t == 0) bstart[c * (NB + 1) + NB] = M;
  cur[t] = excl;
  __syncthreads();
  for (int i = t; i < M; i += 1024) {
    float x = src[3 * i], y = src[3 * i + 1], z = src[3 * i + 2];
    int slot = atomicAdd(&cur[bucket_of(x)], 1);
    sorted[(size_t)c * M + slot] = (float4_t){x, y, z, x * x + y * y + z * z};
  }
}

// ---- kernel B: windowed pair scan ----
#define THREADS 512
#define P 8        // src points per thread (4 packed pairs)
#define S 32       // 16-lane groups per block
#define G 128      // src points per block
#define TILE 64    // targets per group per staging round
#define CHUNK (S * TILE)       // 2048 targets staged per round
#define LSTRIDE (TILE + 1)     // +1 float4 pad -> disjoint banks across groups

__global__ __launch_bounds__(THREADS) void chamfer_min_kernel(
    const float4_t* __restrict__ sorted, const int* __restrict__ bstart,
    float* __restrict__ out, int M, float scale) {
  int blocksPerDir = M / G;
  int pblk = blockIdx.x % blocksPerDir;
  int bd = blockIdx.x / blocksPerDir;
  int dir = bd & 1;
  int b = bd >> 1;
  const float4_t* SP = sorted + (size_t)(2 * b + dir) * M;
  const float4_t* RP = sorted + (size_t)(2 * b + (dir ^ 1)) * M;

  __shared__ float4_t lds[S * LSTRIDE];  // 33.3 KB staging
  __shared__ float pmin[S][G];           // 16 KB per-group per-point mins
  __shared__ int bst[NB + 1];
  __shared__ float red[16];
  __shared__ int wsqb;                   // float-as-int max dist^2

  int t = threadIdx.x;
  int g = t >> 4;  // group 0..31 (uniform per 16 lanes)
  int l = t & 15;

  for (int i = t; i < NB + 1; i += THREADS)
    bst[i] = bstart[(2 * b + (dir ^ 1)) * (NB + 1) + i];

  float cm[P];
  float2_t a2x[P / 2], a2y[P / 2], a2z[P / 2];
  float xmn = 3.0e38f, xmx = -3.0e38f;
  int pbase = pblk * G;
#pragma unroll
  for (int i = 0; i < P / 2; ++i) {
    float4_t v0 = SP[pbase + l + 16 * (2 * i)];
    float4_t v1 = SP[pbase + l + 16 * (2 * i + 1)];
    cm[2 * i] = v0.w;
    cm[2 * i + 1] = v1.w;
    a2x[i] = (float2_t){-2.f * v0.x, -2.f * v1.x};
    a2y[i] = (float2_t){-2.f * v0.y, -2.f * v1.y};
    a2z[i] = (float2_t){-2.f * v0.z, -2.f * v1.z};
    xmn = fminf(xmn, fminf(v0.x, v1.x));
    xmx = fmaxf(xmx, fmaxf(v0.x, v1.x));
  }
  // block reduce x-range
  for (int off = 32; off > 0; off >>= 1) {
    xmn = fminf(xmn, __shfl_down(xmn, off, 64));
    xmx = fmaxf(xmx, __shfl_down(xmx, off, 64));
  }
  if ((t & 63) == 0) { red[t >> 6] = xmn; red[8 + (t >> 6)] = xmx; }
  if (t == 0) wsqb = 0;
  __syncthreads();
  xmn = red[0]; xmx = red[8];
#pragma unroll
  for (int w = 1; w < THREADS / 64; ++w) {
    xmn = fminf(xmn, red[w]);
    xmx = fmaxf(xmx, red[8 + w]);
  }

  float mlo[P / 2], mhi[P / 2];
#pragma unroll
  for (int i = 0; i < P / 2; ++i) { mlo[i] = 3.0e38f; mhi[i] = 3.0e38f; }

  auto scan_range = [&](int lo, int hi) {
    for (int t0 = lo; t0 < hi; t0 += CHUNK) {
      __syncthreads();  // previous readers done before overwrite
#pragma unroll
      for (int r = 0; r < CHUNK / THREADS; ++r) {  // 4 entries/thread
        int e = t + THREADS * r;
        int gi = t0 + e;
        float4_t v = (gi < hi) ? RP[gi] : (float4_t){0.f, 0.f, 0.f, 3.0e38f};
        lds[(e >> 6) * LSTRIDE + (e & 63)] = v;
      }
      __syncthreads();
      if (t0 + TILE * g < hi) {  // group-uniform skip of all-padding tiles
        const float4_t* tp = lds + g * LSTRIDE;
#pragma unroll 2
        for (int j = 0; j < TILE; j += 4) {
          float4_t q0 = tp[j + 0];  // broadcast reads
          float4_t q1 = tp[j + 1];
          float4_t q2 = tp[j + 2];
          float4_t q3 = tp[j + 3];
          float2_t q0xy = __builtin_shufflevector(q0, q0, 0, 1);
          float2_t q0zw = __builtin_shufflevector(q0, q0, 2, 3);
          float2_t q1xy = __builtin_shufflevector(q1, q1, 0, 1);
          float2_t q1zw = __builtin_shufflevector(q1, q1, 2, 3);
          float2_t q2xy = __builtin_shufflevector(q2, q2, 0, 1);
          float2_t q2zw = __builtin_shufflevector(q2, q2, 2, 3);
          float2_t q3xy = __builtin_shufflevector(q3, q3, 0, 1);
          float2_t q3zw = __builtin_shufflevector(q3, q3, 2, 3);
#pragma unroll
          for (int i = 0; i < P / 2; ++i) {
            float2_t d0 = pk_fma_bl(a2x[i], q0xy,
                            pk_fma_bh(a2y[i], q0xy, pk_fma_bl_bh(a2z[i], q0zw)));
            float2_t d1 = pk_fma_bl(a2x[i], q1xy,
                            pk_fma_bh(a2y[i], q1xy, pk_fma_bl_bh(a2z[i], q1zw)));
            float2_t d2 = pk_fma_bl(a2x[i], q2xy,
                            pk_fma_bh(a2y[i], q2xy, pk_fma_bl_bh(a2z[i], q2zw)));
            float2_t d3 = pk_fma_bl(a2x[i], q3xy,
                            pk_fma_bh(a2y[i], q3xy, pk_fma_bl_bh(a2z[i], q3zw)));
            mlo[i] = fminf(fminf(mlo[i], d0.x), d1.x);  // v_min3
            mlo[i] = fminf(fminf(mlo[i], d2.x), d3.x);
            mhi[i] = fminf(fminf(mhi[i], d0.y), d1.y);
            mhi[i] = fminf(fminf(mhi[i], d2.y), d3.y);
          }
        }
      }
    }
  };

  // Phase 1: src bucket range +/- 4 buckets -> per-point upper bound.
  int kb0 = bucket_of(xmn) - 4; if (kb0 < 0) kb0 = 0;
  int kb1 = bucket_of(xmx) + 4; if (kb1 > NB - 1) kb1 = NB - 1;
  int ilo = bst[kb0], ihi = bst[kb1 + 1];
  scan_range(ilo, ihi);

  // W^2 = block-max over points of TRUE dist^2 = cm_p + min_g pmin[g][p].
  // (R5 bug: used the shifted min without cm -> negative -> W ~ 0.)
  __syncthreads();
#pragma unroll
  for (int i = 0; i < P / 2; ++i) {
    pmin[g][l + 16 * (2 * i)] = mlo[i];
    pmin[g][l + 16 * (2 * i + 1)] = mhi[i];
  }
  __syncthreads();
  if (t < G) {
    float mn = 3.0e38f;
#pragma unroll
    for (int s = 0; s < S; ++s) mn = fminf(mn, pmin[s][t]);
    // thread t (t<128) owns point t's cm as cm[t>>4] (l = t&15 matches)
    float dd = fmaxf(cm[t >> 4] + mn, 0.f);
    atomicMax(&wsqb, __float_as_int(dd));  // >=0 floats are int-monotone
  }
  __syncthreads();
  float W = sqrtf(__int_as_float(wsqb));

  // Phase 2: remaining targets in [xmn - W, xmx + W].
  int jlo = bst[bucket_of(xmn - W)];
  int jhi = bst[bucket_of(xmx + W) + 1];
  if (jlo > ilo) jlo = ilo;
  if (jhi < ihi) jhi = ihi;
  scan_range(jlo, ilo);
  scan_range(ihi, jhi);

  // Epilogue: per-point min over groups, add |p|^2, sum, atomic accumulate.
  __syncthreads();
#pragma unroll
  for (int i = 0; i < P / 2; ++i) {
    pmin[g][l + 16 * (2 * i)] = mlo[i];
    pmin[g][l + 16 * (2 * i + 1)] = mhi[i];
  }
  __syncthreads();
  float v = 0.f;
  if (t < G) {
    float mn = 3.0e38f;
#pragma unroll
    for (int s = 0; s < S; ++s) mn = fminf(mn, pmin[s][t]);
    v = cm[t >> 4] + mn;
  }
  for (int off = 32; off > 0; off >>= 1) v += __shfl_down(v, off, 64);
  if ((t & 63) == 0) red[t >> 6] = v;
  __syncthreads();
  if (t == 0) {
    float bsum = 0.f;
#pragma unroll
    for (int w = 0; w < THREADS / 64; ++w) bsum += red[w];
    atomicAdd(out, bsum * scale);
  }
}

extern "C" void kernel_launch(void* const* d_in, const int* in_sizes, int n_in,
                              void* d_out, int out_size, void* d_ws,
                              size_t ws_size, hipStream_t stream) {
  const float* pred = (const float*)d_in[0];
  const float* target = (const float*)d_in[1];
  float* out = (float*)d_out;
  const int B = 4;
  const int M = in_sizes[0] / (B * 3);  // 8192

  float4_t* sorted = (float4_t*)d_ws;  // 2B clouds * M * 16B = 1 MB
  int* bstart = (int*)((char*)d_ws + (size_t)2 * B * M * 16);  // 8*(NB+1) ints

  float scale = 1.0f / (float)(B * M);
  hipMemsetAsync(out, 0, sizeof(float), stream);  // d_out is poisoned 0xAA

  bucket_sort_kernel<<<2 * B, 1024, 0, stream>>>(pred, target, sorted, bstart, M);
  chamfer_min_kernel<<<B * 2 * (M / G), THREADS, 0, stream>>>(sorted, bstart,
                                                              out, M, scale);
}